// Round 5
// baseline (499.366 us; speedup 1.0000x reference)
//
#include <hip/hip_runtime.h>
#include <math.h>

#define BB 32
#define TQQ 2000
#define TKK 512
#define CR 16           // rows (time steps) per chunk (2 rescale halves)
#define HR 8            // rows per rescale half (protocol unit, matches baseline)
#define RS 4            // ring slots, in 16-row chunks (same LDS as 8x8-row)
#define NW 8            // 2 DP waves + 6 producer waves
#define SLOT_F 520      // floats per row slot: p[0..511], pad to 520
#define BRN 64          // boundary ring entries (4 chunks of 16 rows)

__device__ __forceinline__ float dpp_mv_111(float x, float old) {
    return __int_as_float(__builtin_amdgcn_update_dpp(__float_as_int(old), __float_as_int(x), 0x111, 0xf, 0xf, false));
}
__device__ __forceinline__ float dpp_mv_112(float x, float old) {
    return __int_as_float(__builtin_amdgcn_update_dpp(__float_as_int(old), __float_as_int(x), 0x112, 0xf, 0xf, false));
}
__device__ __forceinline__ float dpp_mv_114(float x, float old) {
    return __int_as_float(__builtin_amdgcn_update_dpp(__float_as_int(old), __float_as_int(x), 0x114, 0xf, 0xf, false));
}
__device__ __forceinline__ float dpp_mv_118(float x, float old) {
    return __int_as_float(__builtin_amdgcn_update_dpp(__float_as_int(old), __float_as_int(x), 0x118, 0xf, 0xf, false));
}
__device__ __forceinline__ float dpp_mv_b15(float x, float old) {
    return __int_as_float(__builtin_amdgcn_update_dpp(__float_as_int(old), __float_as_int(x), 0x142, 0xf, 0xf, false));
}
__device__ __forceinline__ float dpp_mv_b31(float x, float old) {
    return __int_as_float(__builtin_amdgcn_update_dpp(__float_as_int(old), __float_as_int(x), 0x143, 0xf, 0xf, false));
}
__device__ __forceinline__ float dpp_wave_shr1(float x, float old) {
    return __int_as_float(__builtin_amdgcn_update_dpp(__float_as_int(old), __float_as_int(x), 0x138, 0xf, 0xf, false));
}

__device__ __forceinline__ float wred_max(float x) {
    x = fmaxf(x, dpp_mv_111(x, -1e38f));
    x = fmaxf(x, dpp_mv_112(x, -1e38f));
    x = fmaxf(x, dpp_mv_114(x, -1e38f));
    x = fmaxf(x, dpp_mv_118(x, -1e38f));
    x = fmaxf(x, dpp_mv_b15(x, -1e38f));
    x = fmaxf(x, dpp_mv_b31(x, -1e38f));
    return __int_as_float(__builtin_amdgcn_readlane(__float_as_int(x), 63));
}
__device__ __forceinline__ float wred_sum(float x) {
    x += dpp_mv_111(x, 0.0f);
    x += dpp_mv_112(x, 0.0f);
    x += dpp_mv_114(x, 0.0f);
    x += dpp_mv_118(x, 0.0f);
    x += dpp_mv_b15(x, 0.0f);
    x += dpp_mv_b31(x, 0.0f);
    return __int_as_float(__builtin_amdgcn_readlane(__float_as_int(x), 63));
}

__device__ __forceinline__ float pow2i(int e) {    // e in [-126, 127]
    return __int_as_float((unsigned)(e + 127) << 23);
}

// one DP step over 4 state-pairs/lane; uses OLD O[i-1] (descending order)
__device__ __forceinline__ void step_quad(float4 p, float pb, float o_prev,
                                          float E[4], float O[4]) {
    float t3 = E[3] + O[2];  O[3] = (O[3] + t3) * p.w;  E[3] = t3 * pb;
    float t2 = E[2] + O[1];  O[2] = (O[2] + t2) * p.z;  E[2] = t2 * pb;
    float t1 = E[1] + O[0];  O[1] = (O[1] + t1) * p.y;  E[1] = t1 * pb;
    float t0 = E[0] + o_prev; O[0] = (O[0] + t0) * p.x; E[0] = t0 * pb;
}

// ---------------------------------------------------------------------------
// Fused kernel v5: proven 2-DP-wave pipeline with 16-row chunks.
// One handshake set (ready-poll, bring-gate, probe, publish) per 16 rows
// instead of per 8; inside each chunk the exact baseline 8-row
// rescale + EF-exchange protocol runs twice (identical numerics cadence).
// pb is staged compactly per slot so DP waves read it as broadcast b128s.
// ---------------------------------------------------------------------------
__global__ __launch_bounds__(NW * 64)
void ForwardSumLoss_77378130805413_kernel(const float* __restrict__ attn,
                                          const int* __restrict__ in_lens,
                                          const int* __restrict__ out_lens,
                                          float* __restrict__ out)
{
    __shared__ float s_slots[RS * CR * SLOT_F];   // 133120 B
    __shared__ float s_pbblk[RS * CR];            // compact pb per slot
    __shared__ float s_dumpE[513];
    __shared__ float s_dumpO[512];
    __shared__ float s_bring[BRN];                // boundary O[255](t) ring, wave0 scale
    __shared__ int   s_ef0[8];                    // wave0 per-HALF exponent ring
    __shared__ int   s_ready[RS];
    __shared__ int   s_w0, s_w1;
    __shared__ int   s_e0c, s_e1c;                // final cumulative exponents

    const int b    = blockIdx.x;
    const int tid  = threadIdx.x;
    const int wave = tid >> 6;
    const int lane = tid & 63;

    int kl = in_lens[b];  kl = kl < 1 ? 1 : (kl > TKK ? TKK : kl);
    int ql = out_lens[b]; ql = ql < 1 ? 1 : (ql > TQQ ? TQQ : ql);
    const int nchunks = (ql + CR - 1) / CR;       // ql >= 512 -> nchunks >= 32

    if (tid < RS)  s_ready[tid] = -1;
    if (tid < BRN) s_bring[tid] = 0.f;
    if (tid == 64) s_w0 = -1;
    if (tid == 65) s_w1 = -1;
    __syncthreads();

    volatile int* vready = s_ready;
    volatile int* vw0    = &s_w0;
    volatile int* vw1    = &s_w1;
    volatile int* vEF0   = s_ef0;

    const float T = 1.0995116e12f;   // 2^40

    if (wave == 0) {
        // ------------- DP wave 0: state pairs m = 0..255 (m = 4*lane + i) -------------
        __builtin_amdgcn_s_setprio(3);
        float E[4] = {0,0,0,0}, O[4] = {0,0,0,0};
        int e0c = 0;
        const int base4 = 4 * lane;
        int rdyN = -9, w1s = -9;

        for (int kk = 0; kk < nchunks; ++kk) {
            const int t0   = kk * CR;
            const int rows = min(ql - t0, CR);
            // bring-ring capacity: wave0 may lead wave1 by at most 3 chunks (BRN=64)
            if (kk >= 3) { while (w1s < kk - 3) { w1s = *vw1; } }
            if (rdyN != kk) { while (vready[kk & (RS - 1)] != kk) {} }
            asm volatile("" ::: "memory");
            const float* bp  = s_slots + (size_t)(kk & (RS - 1)) * CR * SLOT_F;
            const float* pbb = s_pbblk + (kk & (RS - 1)) * CR;

            if (rows == CR) {
                float4 PL[CR]; float PB[CR];
                #pragma unroll
                for (int r = 0; r < CR; ++r)
                    PL[r] = *(const float4*)(bp + r * SLOT_F + base4);
                #pragma unroll
                for (int i = 0; i < CR / 4; ++i) {
                    float4 v = *(const float4*)(pbb + 4 * i);
                    PB[4*i+0] = v.x; PB[4*i+1] = v.y; PB[4*i+2] = v.z; PB[4*i+3] = v.w;
                }
                rdyN = vready[(kk + 1) & (RS - 1)];   // early probes
                w1s  = *vw1;
                #pragma unroll
                for (int h = 0; h < 2; ++h) {
                    #pragma unroll
                    for (int r = 0; r < HR; ++r) {
                        const int rr = h * HR + r;
                        if (kk == 0 && h == 0 && r == 0) {
                            E[0] = (lane == 0) ? PB[0]   * T : 0.f;
                            O[0] = (lane == 0) ? PL[0].x * T : 0.f;
                        } else {
                            float o_prev = dpp_wave_shr1(O[3], 0.0f);
                            step_quad(PL[rr], PB[rr], o_prev, E, O);
                        }
                        if (r < HR - 1) { if (lane == 63) s_bring[(t0 + rr) & (BRN - 1)] = O[3]; }
                    }
                    // 8-row rescale by power of 2 (baseline protocol, per half)
                    float m0 = fmaxf(fmaxf(fmaxf(E[0], E[1]), fmaxf(E[2], E[3])),
                                     fmaxf(fmaxf(O[0], O[1]), fmaxf(O[2], O[3])));
                    m0 = wred_max(m0);
                    int ef = 0;
                    if (m0 > 0.f) ef = 167 - (int)((__float_as_uint(m0) >> 23) & 255);
                    float fh = pow2i(ef - (ef >> 1));
                    float fl = pow2i(ef >> 1);
                    #pragma unroll
                    for (int i = 0; i < 4; ++i) { E[i] = (E[i] * fh) * fl; O[i] = (O[i] * fh) * fl; }
                    e0c += ef;
                    if (lane == 0) vEF0[(2 * kk + h) & 7] = ef;
                    if (lane == 63) s_bring[(t0 + h * HR + HR - 1) & (BRN - 1)] = O[3]; // post-rescale
                }
            } else {
                for (int r = 0; r < rows; ++r) {
                    const float* sq = bp + r * SLOT_F;
                    float4 pl = *(const float4*)(sq + base4);
                    float pb = pbb[r];
                    if (kk == 0 && r == 0) {
                        E[0] = (lane == 0) ? pb   * T : 0.f;
                        O[0] = (lane == 0) ? pl.x * T : 0.f;
                    } else {
                        float o_prev = dpp_wave_shr1(O[3], 0.0f);
                        step_quad(pl, pb, o_prev, E, O);
                    }
                    if (lane == 63) s_bring[(t0 + r) & (BRN - 1)] = O[3];
                }
            }
            asm volatile("" ::: "memory");
            if (lane == 0) *vw0 = kk;
        }
        #pragma unroll
        for (int i = 0; i < 4; ++i) {
            s_dumpE[base4 + i] = E[i];
            s_dumpO[base4 + i] = O[i];
        }
        if (lane == 0) s_e0c = e0c;
    } else if (wave == 1) {
        // ------------- DP wave 1: pairs m = 256..511 + top blank (e512) -------------
        __builtin_amdgcn_s_setprio(3);
        float E[4] = {0,0,0,0}, O[4] = {0,0,0,0}, e512 = 0.f;
        int e0c = 0, e1c = 0;
        const int base4 = 256 + 4 * lane;
        int w0s = -9;

        for (int kk = 0; kk < nchunks; ++kk) {
            const int t0   = kk * CR;
            const int rows = min(ql - t0, CR);
            while (w0s < kk) { w0s = *vw0; }      // wave0 done chunk kk (implies ready)
            asm volatile("" ::: "memory");
            const float* bp  = s_slots + (size_t)(kk & (RS - 1)) * CR * SLOT_F;
            const float* pbb = s_pbblk + (kk & (RS - 1)) * CR;

            if (rows == CR) {
                float4 PL[CR]; float PB[CR];
                #pragma unroll
                for (int r = 0; r < CR; ++r)
                    PL[r] = *(const float4*)(bp + r * SLOT_F + base4);
                #pragma unroll
                for (int i = 0; i < CR / 4; ++i) {
                    float4 v = *(const float4*)(pbb + 4 * i);
                    PB[4*i+0] = v.x; PB[4*i+1] = v.y; PB[4*i+2] = v.z; PB[4*i+3] = v.w;
                }
                w0s = *vw0;                       // early probe
                #pragma unroll
                for (int h = 0; h < 2; ++h) {
                    // boundary conversion factor 2^(e1c - e0c), exact, two-stage
                    int dE = e1c - e0c;
                    dE = dE < -250 ? -250 : (dE > 250 ? 250 : dE);
                    const float Ch = pow2i(dE - (dE >> 1));
                    const float Cl = pow2i(dE >> 1);
                    int ef0k = vEF0[(2 * kk + h) & 7];    // published before vw0 = kk
                    float BND[HR];
                    #pragma unroll
                    for (int r = 0; r < HR; ++r)
                        BND[r] = (s_bring[(t0 + h * HR - 1 + r) & (BRN - 1)] * Ch) * Cl;
                    #pragma unroll
                    for (int r = 0; r < HR; ++r) {
                        const int rr = h * HR + r;
                        float o_prev = dpp_wave_shr1(O[3], 0.0f);
                        o_prev = (lane == 0) ? BND[r] : o_prev;
                        float te = e512 + O[3]; e512 = te * PB[rr];  // old O[3] (lane63 = m511)
                        step_quad(PL[rr], PB[rr], o_prev, E, O);
                    }
                    float m1 = fmaxf(fmaxf(fmaxf(E[0], E[1]), fmaxf(E[2], E[3])),
                                     fmaxf(fmaxf(O[0], O[1]), fmaxf(O[2], O[3])));
                    m1 = fmaxf(m1, e512);
                    m1 = wred_max(m1);
                    int ef1 = (m1 > 0.f) ? (167 - (int)((__float_as_uint(m1) >> 23) & 255))
                                         : ef0k;   // no mass: track wave0, freeze delta
                    float fh = pow2i(ef1 - (ef1 >> 1));
                    float fl = pow2i(ef1 >> 1);
                    #pragma unroll
                    for (int i = 0; i < 4; ++i) { E[i] = (E[i] * fh) * fl; O[i] = (O[i] * fh) * fl; }
                    e512 = (e512 * fh) * fl;
                    e1c += ef1;
                    e0c += ef0k;
                }
            } else {
                int dE = e1c - e0c;
                dE = dE < -250 ? -250 : (dE > 250 ? 250 : dE);
                const float Ch = pow2i(dE - (dE >> 1));
                const float Cl = pow2i(dE >> 1);
                for (int r = 0; r < rows; ++r) {
                    const float* sq = bp + r * SLOT_F;
                    float4 pl = *(const float4*)(sq + base4);
                    float pb = pbb[r];
                    float bnd = (s_bring[(t0 - 1 + r) & (BRN - 1)] * Ch) * Cl;
                    float o_prev = dpp_wave_shr1(O[3], 0.0f);
                    o_prev = (lane == 0) ? bnd : o_prev;
                    float te = e512 + O[3]; e512 = te * pb;
                    step_quad(pl, pb, o_prev, E, O);
                }
            }
            asm volatile("" ::: "memory");
            if (lane == 0) *vw1 = kk;
        }
        #pragma unroll
        for (int i = 0; i < 4; ++i) {
            s_dumpE[base4 + i] = E[i];
            s_dumpO[base4 + i] = O[i];
        }
        if (lane == 63) s_dumpE[512] = e512;
        if (lane == 0)  s_e1c = e1c;
    } else {
        // ------------- producer waves (6): softmax one 16-row chunk, 2 halves -------------
        const int pidx = wave - 2;                  // 0..5
        const float* base = attn + (size_t)b * TQQ * TKK;
        const int j0 = 8 * lane;

        for (int c = pidx; c < nchunks; c += NW - 2) {
            const int tc0 = c * CR;
            while (*vw1 < c - RS) { __builtin_amdgcn_s_sleep(4); }   // slot freed by wave1
            asm volatile("" ::: "memory");
            float* bp  = s_slots + (size_t)(c & (RS - 1)) * CR * SLOT_F;
            float* pbb = s_pbblk + (c & (RS - 1)) * CR;

            #pragma unroll
            for (int h = 0; h < 2; ++h) {
                float4 x0[HR], x1[HR];
                #pragma unroll
                for (int r = 0; r < HR; ++r) {
                    x0[r] = make_float4(-1e30f, -1e30f, -1e30f, -1e30f);
                    x1[r] = x0[r];
                    const int t = tc0 + h * HR + r;
                    if (t < ql) {
                        const float* row = base + (size_t)t * TKK;
                        if (j0 < kl)     x0[r] = *(const float4*)(row + j0);
                        if (j0 + 4 < kl) x1[r] = *(const float4*)(row + j0 + 4);
                    }
                }
                #pragma unroll
                for (int r = 0; r < HR; ++r) {
                    const int t = tc0 + h * HR + r;
                    if (t >= ql) continue;
                    float va[8] = {x0[r].x, x0[r].y, x0[r].z, x0[r].w,
                                   x1[r].x, x1[r].y, x1[r].z, x1[r].w};
                    float m = -1.0f;  // blank logprob
                    #pragma unroll
                    for (int cc = 0; cc < 8; ++cc) if (j0 + cc < kl) m = fmaxf(m, va[cc]);
                    m = wred_max(m);
                    float pv[8]; float vsum = 0.f;
                    #pragma unroll
                    for (int cc = 0; cc < 8; ++cc) {
                        pv[cc] = (j0 + cc < kl) ? __expf(va[cc] - m) : 0.f;
                        vsum += pv[cc];
                    }
                    vsum = wred_sum(vsum);
                    float vb   = __expf(-1.0f - m);
                    float rinv = 1.0f / (vsum + vb);
                    float* sp = bp + (size_t)(h * HR + r) * SLOT_F;
                    *(float4*)(sp + j0)     = make_float4(pv[0]*rinv, pv[1]*rinv, pv[2]*rinv, pv[3]*rinv);
                    *(float4*)(sp + j0 + 4) = make_float4(pv[4]*rinv, pv[5]*rinv, pv[6]*rinv, pv[7]*rinv);
                    if (lane == 0) pbb[h * HR + r] = vb * rinv;
                }
            }
            __threadfence_block();
            if (lane == 0) vready[c & (RS - 1)] = c;
        }
    }

    __syncthreads();
    if (tid == 0) {
        const double logTd = 27.725887222397812;   // 40*ln2
        const double LN2d  = 0.69314718055994531;
        float aE = s_dumpE[kl];
        float aO = s_dumpO[kl - 1];
        int e0c = s_e0c, e1c = s_e1c;
        double sE = logTd + (double)((kl     >= 256) ? e1c : e0c) * LN2d;
        double sO = logTd + (double)((kl - 1 >= 256) ? e1c : e0c) * LN2d;
        double lE = (aE > 0.f) ? log((double)aE) - sE : -1e300;
        double lO = (aO > 0.f) ? log((double)aO) - sO : -1e300;
        double mx = fmax(lE, lO);
        double ll = (mx < -1e290) ? -745.0 : mx + log(exp(lE - mx) + exp(lO - mx));
        float val = (float)(-ll / ((double)kl * (double)BB));
        atomicAdd(out, val);
    }
}

extern "C" void kernel_launch(void* const* d_in, const int* in_sizes, int n_in,
                              void* d_out, int out_size, void* d_ws, size_t ws_size,
                              hipStream_t stream) {
    const float* attn     = (const float*)d_in[0];
    const int*   in_lens  = (const int*)d_in[1];
    const int*   out_lens = (const int*)d_in[2];
    float* out = (float*)d_out;
    hipMemsetAsync(out, 0, sizeof(float), stream);
    hipLaunchKernelGGL(ForwardSumLoss_77378130805413_kernel,
                       dim3(BB), dim3(NW * 64), 0, stream,
                       attn, in_lens, out_lens, out);
}

// Round 8
// 410.956 us; speedup vs baseline: 1.2151x; 1.2151x over previous
//
#include <hip/hip_runtime.h>
#include <math.h>

#define BB 32
#define TQQ 2000
#define TKK 512
#define CR 8            // rows (time steps) per chunk
#define RS 8            // ring slots, in chunks
#define NW 8            // 2 DP waves + 6 producer waves
#define SLOT_F 520      // floats per row slot: p[0..511], pad to 520 (2080 B/row)
#define LEAD 5          // wave0 may lead wave1 by at most LEAD chunks (< RS-1)

typedef float f32x4 __attribute__((ext_vector_type(4)));

#define AS3F(p) ((const __attribute__((address_space(3))) float*)(p))

__device__ __forceinline__ float dpp_mv_111(float x, float old) {
    return __int_as_float(__builtin_amdgcn_update_dpp(__float_as_int(old), __float_as_int(x), 0x111, 0xf, 0xf, false));
}
__device__ __forceinline__ float dpp_mv_112(float x, float old) {
    return __int_as_float(__builtin_amdgcn_update_dpp(__float_as_int(old), __float_as_int(x), 0x112, 0xf, 0xf, false));
}
__device__ __forceinline__ float dpp_mv_114(float x, float old) {
    return __int_as_float(__builtin_amdgcn_update_dpp(__float_as_int(old), __float_as_int(x), 0x114, 0xf, 0xf, false));
}
__device__ __forceinline__ float dpp_mv_118(float x, float old) {
    return __int_as_float(__builtin_amdgcn_update_dpp(__float_as_int(old), __float_as_int(x), 0x118, 0xf, 0xf, false));
}
__device__ __forceinline__ float dpp_mv_b15(float x, float old) {
    return __int_as_float(__builtin_amdgcn_update_dpp(__float_as_int(old), __float_as_int(x), 0x142, 0xf, 0xf, false));
}
__device__ __forceinline__ float dpp_mv_b31(float x, float old) {
    return __int_as_float(__builtin_amdgcn_update_dpp(__float_as_int(old), __float_as_int(x), 0x143, 0xf, 0xf, false));
}
__device__ __forceinline__ float dpp_wave_shr1(float x, float old) {
    return __int_as_float(__builtin_amdgcn_update_dpp(__float_as_int(old), __float_as_int(x), 0x138, 0xf, 0xf, false));
}

__device__ __forceinline__ float wred_max(float x) {
    x = fmaxf(x, dpp_mv_111(x, -1e38f));
    x = fmaxf(x, dpp_mv_112(x, -1e38f));
    x = fmaxf(x, dpp_mv_114(x, -1e38f));
    x = fmaxf(x, dpp_mv_118(x, -1e38f));
    x = fmaxf(x, dpp_mv_b15(x, -1e38f));
    x = fmaxf(x, dpp_mv_b31(x, -1e38f));
    return __int_as_float(__builtin_amdgcn_readlane(__float_as_int(x), 63));
}
__device__ __forceinline__ float wred_sum(float x) {
    x += dpp_mv_111(x, 0.0f);
    x += dpp_mv_112(x, 0.0f);
    x += dpp_mv_114(x, 0.0f);
    x += dpp_mv_118(x, 0.0f);
    x += dpp_mv_b15(x, 0.0f);
    x += dpp_mv_b31(x, 0.0f);
    return __int_as_float(__builtin_amdgcn_readlane(__float_as_int(x), 63));
}

__device__ __forceinline__ float pow2i(int e) {    // e in [-126, 127]
    return __int_as_float((unsigned)(e + 127) << 23);
}

// one DP step over 4 state-pairs/lane; uses OLD O[i-1] (descending order)
__device__ __forceinline__ void step_quad(f32x4 p, float pb, float o_prev,
                                          float E[4], float O[4]) {
    float t3 = E[3] + O[2];  O[3] = (O[3] + t3) * p.w;  E[3] = t3 * pb;
    float t2 = E[2] + O[1];  O[2] = (O[2] + t2) * p.z;  E[2] = t2 * pb;
    float t1 = E[1] + O[0];  O[1] = (O[1] + t1) * p.y;  E[1] = t1 * pb;
    float t0 = E[0] + o_prev; O[0] = (O[0] + t0) * p.x; E[0] = t0 * pb;
}

// ---------------------------------------------------------------------------
// v6: baseline 2-DP-wave structure + inline-asm software pipeline.
// asm volatile ds_reads are program-ordered, so chunk k+1's loads genuinely
// issue before chunk k's compute and retire underneath it. Protocol (8-row
// rescale, EF exchange, boundary ring semantics) identical to the 222us
// baseline; layout: compact s_pb, per-slot bring ring + register carry.
// ---------------------------------------------------------------------------
__global__ __launch_bounds__(NW * 64)
void ForwardSumLoss_77378130805413_kernel(const float* __restrict__ attn,
                                          const int* __restrict__ in_lens,
                                          const int* __restrict__ out_lens,
                                          float* __restrict__ out)
{
    __shared__ float s_slots[RS * CR * SLOT_F];   // 133120 B
    __shared__ float s_pb[RS * CR];               // compact pb per slot
    __shared__ float s_bringS[RS * CR];           // per-slot boundary ring
    __shared__ float s_dumpE[513];
    __shared__ float s_dumpO[512];
    __shared__ int   s_ef0[RS];                   // wave0 per-chunk exponent ring
    __shared__ int   s_ready[RS];
    __shared__ int   s_w0, s_w1;
    __shared__ int   s_e0c, s_e1c;

    const int b    = blockIdx.x;
    const int tid  = threadIdx.x;
    const int wave = tid >> 6;
    const int lane = tid & 63;

    int kl = in_lens[b];  kl = kl < 1 ? 1 : (kl > TKK ? TKK : kl);
    int ql = out_lens[b]; ql = ql < 1 ? 1 : (ql > TQQ ? TQQ : ql);
    const int fullc   = ql >> 3;                  // full 8-row chunks
    const int nchunks = (ql + CR - 1) / CR;

    if (tid < RS)  s_ready[tid] = -1;
    if (tid >= 64 && tid < 64 + RS * CR) s_bringS[tid - 64] = 0.f;
    if (tid == 128) s_w0 = -1;
    if (tid == 129) s_w1 = -1;
    __syncthreads();

    volatile int* vready = s_ready;
    volatile int* vw0    = &s_w0;
    volatile int* vw1    = &s_w1;
    volatile int* vEF0   = s_ef0;

    const float T = 1.0995116e12f;   // 2^40

    if (wave == 0) {
        // ------------- DP wave 0: state pairs m = 0..255 (m = 4*lane + i) -------------
        __builtin_amdgcn_s_setprio(3);
        float E[4] = {0,0,0,0}, O[4] = {0,0,0,0};
        int e0c = 0;
        const int base4 = 4 * lane;
        const unsigned aSlot0 = (unsigned)(unsigned long long)AS3F(s_slots) + (unsigned)(base4 * 4);
        const unsigned aPbB   = (unsigned)(unsigned long long)AS3F(s_pb);
        int rdyN = -9, w1s = -1;
        int k = 0;

        f32x4 A0={0,0,0,0},A1={0,0,0,0},A2={0,0,0,0},A3={0,0,0,0},A4={0,0,0,0},A5={0,0,0,0},A6={0,0,0,0},A7={0,0,0,0},Ap0={0,0,0,0},Ap1={0,0,0,0};
        f32x4 B0={0,0,0,0},B1={0,0,0,0},B2={0,0,0,0},B3={0,0,0,0},B4={0,0,0,0},B5={0,0,0,0},B6={0,0,0,0},B7={0,0,0,0},Bp0={0,0,0,0},Bp1={0,0,0,0};

#define W0_ISSUE(S, kk) do {                                                  \
    unsigned a_ = aSlot0 + (unsigned)((((kk) & (RS - 1)) * CR * SLOT_F) * 4); \
    asm volatile("ds_read_b128 %0, %1 offset:0"     : "=v"(S##0) : "v"(a_));  \
    asm volatile("ds_read_b128 %0, %1 offset:2080"  : "=v"(S##1) : "v"(a_));  \
    asm volatile("ds_read_b128 %0, %1 offset:4160"  : "=v"(S##2) : "v"(a_));  \
    asm volatile("ds_read_b128 %0, %1 offset:6240"  : "=v"(S##3) : "v"(a_));  \
    asm volatile("ds_read_b128 %0, %1 offset:8320"  : "=v"(S##4) : "v"(a_));  \
    asm volatile("ds_read_b128 %0, %1 offset:10400" : "=v"(S##5) : "v"(a_));  \
    asm volatile("ds_read_b128 %0, %1 offset:12480" : "=v"(S##6) : "v"(a_));  \
    asm volatile("ds_read_b128 %0, %1 offset:14560" : "=v"(S##7) : "v"(a_));  \
    unsigned q_ = aPbB + (unsigned)((((kk) & (RS - 1)) * CR) * 4);            \
    asm volatile("ds_read_b128 %0, %1 offset:0"  : "=v"(S##p0) : "v"(q_));    \
    asm volatile("ds_read_b128 %0, %1 offset:16" : "=v"(S##p1) : "v"(q_));    \
} while (0)

#define W0_STEP(CUR, NXT)                                                     \
    do {                                                                      \
        asm volatile("s_waitcnt lgkmcnt(0)" ::: "memory");                    \
        __builtin_amdgcn_sched_barrier(0);                                    \
        if (k + 1 < fullc) {                                                  \
            if (rdyN != k + 1) {                                              \
                do { rdyN = vready[(k + 1) & (RS - 1)]; } while (rdyN != k + 1); \
                asm volatile("" ::: "memory");                                \
            }                                                                 \
            W0_ISSUE(NXT, k + 1);                                             \
            __builtin_amdgcn_sched_barrier(0);                                \
        }                                                                     \
        if (w1s < k - LEAD) {                                                 \
            do { w1s = *vw1; } while (w1s < k - LEAD);                        \
            asm volatile("" ::: "memory");                                    \
        }                                                                     \
        {                                                                     \
            f32x4 PA_[CR] = {CUR##0, CUR##1, CUR##2, CUR##3,                  \
                             CUR##4, CUR##5, CUR##6, CUR##7};                 \
            float PB_[CR] = {CUR##p0.x, CUR##p0.y, CUR##p0.z, CUR##p0.w,      \
                             CUR##p1.x, CUR##p1.y, CUR##p1.z, CUR##p1.w};     \
            _Pragma("unroll")                                                 \
            for (int r = 0; r < CR; ++r) {                                    \
                if (k == 0 && r == 0) {                                       \
                    E[0] = (lane == 0) ? PB_[0]   * T : 0.f;                  \
                    O[0] = (lane == 0) ? PA_[0].x * T : 0.f;                  \
                } else {                                                      \
                    float o_prev = dpp_wave_shr1(O[3], 0.0f);                 \
                    step_quad(PA_[r], PB_[r], o_prev, E, O);                  \
                }                                                             \
                if (r < CR - 1) { if (lane == 63) s_bringS[(k & (RS - 1)) * CR + r] = O[3]; } \
            }                                                                 \
            float m0_ = fmaxf(fmaxf(fmaxf(E[0], E[1]), fmaxf(E[2], E[3])),    \
                              fmaxf(fmaxf(O[0], O[1]), fmaxf(O[2], O[3])));   \
            m0_ = wred_max(m0_);                                              \
            int ef_ = 0;                                                      \
            if (m0_ > 0.f) ef_ = 167 - (int)((__float_as_uint(m0_) >> 23) & 255); \
            float fh_ = pow2i(ef_ - (ef_ >> 1));                              \
            float fl_ = pow2i(ef_ >> 1);                                      \
            _Pragma("unroll")                                                 \
            for (int i = 0; i < 4; ++i) { E[i] = (E[i]*fh_)*fl_; O[i] = (O[i]*fh_)*fl_; } \
            e0c += ef_;                                                       \
            if (lane == 0) vEF0[k & (RS - 1)] = ef_;                          \
            if (lane == 63) s_bringS[(k & (RS - 1)) * CR + (CR - 1)] = O[3];  \
        }                                                                     \
        asm volatile("" ::: "memory");                                        \
        if (lane == 0) *vw0 = k;                                              \
        w1s  = *vw1;                                                          \
        rdyN = vready[(k + 2) & (RS - 1)];                                    \
    } while (0)

        if (fullc > 0) {
            while (vready[0] != 0) {}
            asm volatile("" ::: "memory");
            W0_ISSUE(A, 0);
            for (;;) {
                W0_STEP(A, B); if (++k >= fullc) break;
                W0_STEP(B, A); if (++k >= fullc) break;
            }
        }
        // tail chunk (rows < CR), non-pipelined baseline path
        if (nchunks > fullc) {
            const int rows = ql - k * CR;
            if (w1s < k - LEAD) { do { w1s = *vw1; } while (w1s < k - LEAD); }
            while (vready[k & (RS - 1)] != k) {}
            asm volatile("" ::: "memory");
            const float* bp  = s_slots + (size_t)(k & (RS - 1)) * CR * SLOT_F;
            const float* pbb = s_pb + (k & (RS - 1)) * CR;
            for (int r = 0; r < rows; ++r) {
                f32x4 pl = *(const f32x4*)(bp + r * SLOT_F + base4);
                float pb = pbb[r];
                if (k == 0 && r == 0) {
                    E[0] = (lane == 0) ? pb   * T : 0.f;
                    O[0] = (lane == 0) ? pl.x * T : 0.f;
                } else {
                    float o_prev = dpp_wave_shr1(O[3], 0.0f);
                    step_quad(pl, pb, o_prev, E, O);
                }
                if (lane == 63) s_bringS[(k & (RS - 1)) * CR + r] = O[3];
            }
            asm volatile("" ::: "memory");
            if (lane == 0) *vw0 = k;
        }
#undef W0_STEP
#undef W0_ISSUE
        #pragma unroll
        for (int i = 0; i < 4; ++i) {
            s_dumpE[base4 + i] = E[i];
            s_dumpO[base4 + i] = O[i];
        }
        if (lane == 0) s_e0c = e0c;
    } else if (wave == 1) {
        // ------------- DP wave 1: pairs m = 256..511 + top blank (e512) -------------
        __builtin_amdgcn_s_setprio(3);
        float E[4] = {0,0,0,0}, O[4] = {0,0,0,0}, e512 = 0.f, prev7 = 0.f;
        int e0c = 0, e1c = 0;
        const int base4 = 256 + 4 * lane;
        const unsigned aSlot0 = (unsigned)(unsigned long long)AS3F(s_slots) + (unsigned)(base4 * 4);
        const unsigned aPbB   = (unsigned)(unsigned long long)AS3F(s_pb);
        const unsigned aBrB   = (unsigned)(unsigned long long)AS3F(s_bringS);
        const unsigned aEfB   = (unsigned)(unsigned long long)AS3F((const float*)s_ef0);
        int w0s = -1;
        int k = 0;

        f32x4 A0={0,0,0,0},A1={0,0,0,0},A2={0,0,0,0},A3={0,0,0,0},A4={0,0,0,0},A5={0,0,0,0},A6={0,0,0,0},A7={0,0,0,0},Ap0={0,0,0,0},Ap1={0,0,0,0},Ab0={0,0,0,0},Ab1={0,0,0,0};
        f32x4 B0={0,0,0,0},B1={0,0,0,0},B2={0,0,0,0},B3={0,0,0,0},B4={0,0,0,0},B5={0,0,0,0},B6={0,0,0,0},B7={0,0,0,0},Bp0={0,0,0,0},Bp1={0,0,0,0},Bb0={0,0,0,0},Bb1={0,0,0,0};
        int Ae_ = 0, Be_ = 0;

#define W1_ISSUE(S, kk) do {                                                  \
    unsigned a_ = aSlot0 + (unsigned)((((kk) & (RS - 1)) * CR * SLOT_F) * 4); \
    asm volatile("ds_read_b128 %0, %1 offset:0"     : "=v"(S##0) : "v"(a_));  \
    asm volatile("ds_read_b128 %0, %1 offset:2080"  : "=v"(S##1) : "v"(a_));  \
    asm volatile("ds_read_b128 %0, %1 offset:4160"  : "=v"(S##2) : "v"(a_));  \
    asm volatile("ds_read_b128 %0, %1 offset:6240"  : "=v"(S##3) : "v"(a_));  \
    asm volatile("ds_read_b128 %0, %1 offset:8320"  : "=v"(S##4) : "v"(a_));  \
    asm volatile("ds_read_b128 %0, %1 offset:10400" : "=v"(S##5) : "v"(a_));  \
    asm volatile("ds_read_b128 %0, %1 offset:12480" : "=v"(S##6) : "v"(a_));  \
    asm volatile("ds_read_b128 %0, %1 offset:14560" : "=v"(S##7) : "v"(a_));  \
    unsigned q_ = aPbB + (unsigned)((((kk) & (RS - 1)) * CR) * 4);            \
    asm volatile("ds_read_b128 %0, %1 offset:0"  : "=v"(S##p0) : "v"(q_));    \
    asm volatile("ds_read_b128 %0, %1 offset:16" : "=v"(S##p1) : "v"(q_));    \
    unsigned r_ = aBrB + (unsigned)((((kk) & (RS - 1)) * CR) * 4);            \
    asm volatile("ds_read_b128 %0, %1 offset:0"  : "=v"(S##b0) : "v"(r_));    \
    asm volatile("ds_read_b128 %0, %1 offset:16" : "=v"(S##b1) : "v"(r_));    \
    unsigned e_ = aEfB + (unsigned)(((kk) & (RS - 1)) * 4);                   \
    asm volatile("ds_read_b32 %0, %1" : "=v"(S##e_) : "v"(e_));               \
} while (0)

#define W1_STEP(CUR, NXT)                                                     \
    do {                                                                      \
        asm volatile("s_waitcnt lgkmcnt(0)" ::: "memory");                    \
        __builtin_amdgcn_sched_barrier(0);                                    \
        if (k + 1 < fullc) {                                                  \
            if (w0s < k + 1) {                                                \
                do { w0s = *vw0; } while (w0s < k + 1);                       \
                asm volatile("" ::: "memory");                                \
            }                                                                 \
            W1_ISSUE(NXT, k + 1);                                             \
            __builtin_amdgcn_sched_barrier(0);                                \
        }                                                                     \
        {                                                                     \
            int dE_ = e1c - e0c;                                              \
            dE_ = dE_ < -250 ? -250 : (dE_ > 250 ? 250 : dE_);                \
            const float Ch_ = pow2i(dE_ - (dE_ >> 1));                        \
            const float Cl_ = pow2i(dE_ >> 1);                                \
            int ef0k_ = CUR##e_;                                              \
            f32x4 PA_[CR] = {CUR##0, CUR##1, CUR##2, CUR##3,                  \
                             CUR##4, CUR##5, CUR##6, CUR##7};                 \
            float PB_[CR] = {CUR##p0.x, CUR##p0.y, CUR##p0.z, CUR##p0.w,      \
                             CUR##p1.x, CUR##p1.y, CUR##p1.z, CUR##p1.w};     \
            float BR_[CR] = {prev7, CUR##b0.x, CUR##b0.y, CUR##b0.z,          \
                             CUR##b0.w, CUR##b1.x, CUR##b1.y, CUR##b1.z};     \
            _Pragma("unroll")                                                 \
            for (int r = 0; r < CR; ++r) {                                    \
                float bnd_ = (BR_[r] * Ch_) * Cl_;                            \
                float o_prev = dpp_wave_shr1(O[3], 0.0f);                     \
                o_prev = (lane == 0) ? bnd_ : o_prev;                         \
                float te_ = e512 + O[3]; e512 = te_ * PB_[r];                 \
                step_quad(PA_[r], PB_[r], o_prev, E, O);                      \
            }                                                                 \
            float m1_ = fmaxf(fmaxf(fmaxf(E[0], E[1]), fmaxf(E[2], E[3])),    \
                              fmaxf(fmaxf(O[0], O[1]), fmaxf(O[2], O[3])));   \
            m1_ = fmaxf(m1_, e512);                                           \
            m1_ = wred_max(m1_);                                              \
            int ef1_ = (m1_ > 0.f) ? (167 - (int)((__float_as_uint(m1_) >> 23) & 255)) \
                                   : ef0k_;                                   \
            float fh_ = pow2i(ef1_ - (ef1_ >> 1));                            \
            float fl_ = pow2i(ef1_ >> 1);                                     \
            _Pragma("unroll")                                                 \
            for (int i = 0; i < 4; ++i) { E[i] = (E[i]*fh_)*fl_; O[i] = (O[i]*fh_)*fl_; } \
            e512 = (e512 * fh_) * fl_;                                        \
            e1c += ef1_;                                                      \
            e0c += ef0k_;                                                     \
            prev7 = CUR##b1.w;                                                \
        }                                                                     \
        asm volatile("" ::: "memory");                                        \
        if (lane == 0) *vw1 = k;                                              \
        w0s = *vw0;                                                           \
    } while (0)

        if (fullc > 0) {
            do { w0s = *vw0; } while (w0s < 0);
            asm volatile("" ::: "memory");
            W1_ISSUE(A, 0);
            for (;;) {
                W1_STEP(A, B); if (++k >= fullc) break;
                W1_STEP(B, A); if (++k >= fullc) break;
            }
        }
        // tail chunk (rows < CR)
        if (nchunks > fullc) {
            const int rows = ql - k * CR;
            while (w0s < k) { w0s = *vw0; }
            asm volatile("" ::: "memory");
            int dE = e1c - e0c;
            dE = dE < -250 ? -250 : (dE > 250 ? 250 : dE);
            const float Ch = pow2i(dE - (dE >> 1));
            const float Cl = pow2i(dE >> 1);
            const float* bp  = s_slots + (size_t)(k & (RS - 1)) * CR * SLOT_F;
            const float* pbb = s_pb + (k & (RS - 1)) * CR;
            for (int r = 0; r < rows; ++r) {
                f32x4 pl = *(const f32x4*)(bp + r * SLOT_F + base4);
                float pb = pbb[r];
                float braw = (r == 0) ? prev7 : s_bringS[(k & (RS - 1)) * CR + (r - 1)];
                float bnd = (braw * Ch) * Cl;
                float o_prev = dpp_wave_shr1(O[3], 0.0f);
                o_prev = (lane == 0) ? bnd : o_prev;
                float te = e512 + O[3]; e512 = te * pb;
                step_quad(pl, pb, o_prev, E, O);
            }
            asm volatile("" ::: "memory");
            if (lane == 0) *vw1 = k;
        }
#undef W1_STEP
#undef W1_ISSUE
        #pragma unroll
        for (int i = 0; i < 4; ++i) {
            s_dumpE[base4 + i] = E[i];
            s_dumpO[base4 + i] = O[i];
        }
        if (lane == 63) s_dumpE[512] = e512;
        if (lane == 0)  s_e1c = e1c;
    } else {
        // ------------- producer waves (6): softmax one chunk each -------------
        const int pidx = wave - 2;                  // 0..5
        const float* base = attn + (size_t)b * TQQ * TKK;
        const int j0 = 8 * lane;

        for (int c = pidx; c < nchunks; c += NW - 2) {
            const int t0 = c * CR;
            while (*vw1 < c - RS) { __builtin_amdgcn_s_sleep(4); }   // slot freed by wave1
            asm volatile("" ::: "memory");

            float4 x0[CR], x1[CR];
            #pragma unroll
            for (int r = 0; r < CR; ++r) {
                x0[r] = make_float4(-1e30f, -1e30f, -1e30f, -1e30f);
                x1[r] = x0[r];
                const int t = t0 + r;
                if (t < ql) {
                    const float* row = base + (size_t)t * TKK;
                    if (j0 < kl)     x0[r] = *(const float4*)(row + j0);
                    if (j0 + 4 < kl) x1[r] = *(const float4*)(row + j0 + 4);
                }
            }
            float* bp = s_slots + (size_t)(c & (RS - 1)) * CR * SLOT_F;
            #pragma unroll
            for (int r = 0; r < CR; ++r) {
                const int t = t0 + r;
                if (t >= ql) continue;
                float va[8] = {x0[r].x, x0[r].y, x0[r].z, x0[r].w,
                               x1[r].x, x1[r].y, x1[r].z, x1[r].w};
                float m = -1.0f;  // blank logprob
                #pragma unroll
                for (int cc = 0; cc < 8; ++cc) if (j0 + cc < kl) m = fmaxf(m, va[cc]);
                m = wred_max(m);
                float pv[8]; float vsum = 0.f;
                #pragma unroll
                for (int cc = 0; cc < 8; ++cc) {
                    pv[cc] = (j0 + cc < kl) ? __expf(va[cc] - m) : 0.f;
                    vsum += pv[cc];
                }
                vsum = wred_sum(vsum);
                float vb   = __expf(-1.0f - m);
                float rinv = 1.0f / (vsum + vb);
                float* sp = bp + (size_t)r * SLOT_F;
                *(float4*)(sp + j0)     = make_float4(pv[0]*rinv, pv[1]*rinv, pv[2]*rinv, pv[3]*rinv);
                *(float4*)(sp + j0 + 4) = make_float4(pv[4]*rinv, pv[5]*rinv, pv[6]*rinv, pv[7]*rinv);
                if (lane == 0) s_pb[(c & (RS - 1)) * CR + r] = vb * rinv;
            }
            __threadfence_block();
            if (lane == 0) vready[c & (RS - 1)] = c;
        }
    }

    __syncthreads();
    if (tid == 0) {
        const double logTd = 27.725887222397812;   // 40*ln2
        const double LN2d  = 0.69314718055994531;
        float aE = s_dumpE[kl];
        float aO = s_dumpO[kl - 1];
        int e0c = s_e0c, e1c = s_e1c;
        double sE = logTd + (double)((kl     >= 256) ? e1c : e0c) * LN2d;
        double sO = logTd + (double)((kl - 1 >= 256) ? e1c : e0c) * LN2d;
        double lE = (aE > 0.f) ? log((double)aE) - sE : -1e300;
        double lO = (aO > 0.f) ? log((double)aO) - sO : -1e300;
        double mx = fmax(lE, lO);
        double ll = (mx < -1e290) ? -745.0 : mx + log(exp(lE - mx) + exp(lO - mx));
        float val = (float)(-ll / ((double)kl * (double)BB));
        atomicAdd(out, val);
    }
}

extern "C" void kernel_launch(void* const* d_in, const int* in_sizes, int n_in,
                              void* d_out, int out_size, void* d_ws, size_t ws_size,
                              hipStream_t stream) {
    const float* attn     = (const float*)d_in[0];
    const int*   in_lens  = (const int*)d_in[1];
    const int*   out_lens = (const int*)d_in[2];
    float* out = (float*)d_out;
    hipMemsetAsync(out, 0, sizeof(float), stream);
    hipLaunchKernelGGL(ForwardSumLoss_77378130805413_kernel,
                       dim3(BB), dim3(NW * 64), 0, stream,
                       attn, in_lens, out_lens, out);
}